// Round 8
// baseline (262.126 us; speedup 1.0000x reference)
//
#include <hip/hip_runtime.h>
#include <math.h>

// N=4, C=256, H=W=32, NH=2, HD=128, MAX_DIS=7, WS=15, WW=225, T=sqrt(128)
// out: [hw=1024][n=4][c=256] fp32
//
// Wfc folded backward through PV:
//   Wc_g  = Wfc[:,g*128:+128] @ Wv[g*128:+128,:]   (256x256 per head)
//   bc_g  = Wfc[:,gs] @ bv[gs]                      (256 per head)
//   Vb'_g = Wfc[:,gs] @ Vb[g]                       (256 x 225 per head)
//   out[m,n,:] = sum_g P_g . (V'_g_un + Vb'_g) + bfc,  V'_g = Wc_g x + bc_g
// -> mfma_fc kernel and AG intermediate deleted; scores atomicAdds fp32 out.

typedef __attribute__((ext_vector_type(8))) short short8;
typedef __attribute__((ext_vector_type(4))) float floatx4;

__device__ __forceinline__ short f2bf(float f) {
    unsigned u = __float_as_uint(f);
    unsigned r = (u + 0x7fffu + ((u >> 16) & 1u)) >> 16;
    return (short)r;
}
__device__ __forceinline__ float bf2f(short s) {
    return __uint_as_float(((unsigned)(unsigned short)s) << 16);
}

// ---------------------------------------------------------------------------
// prep: all weight-side work. grid 158 blocks x 256 threads.
//  u [0,32)   : Wc_g = Wfc_g @ Wv_g (fp32) -> A-frags (Whi sel 2+g); bc_g.
//  u [32,64)  : Vb'_g = Wfc_g @ Vb_g (fp32) -> row-major hi/lo (Vbh/Vbl).
//  u [64,128) : Wq/Wk A-frags.
//  u [128,158): Wrel frags.
// ---------------------------------------------------------------------------
__global__ __launch_bounds__(256)
void prep(const float* __restrict__ Wq, const float* __restrict__ Wk,
          const float* __restrict__ Wv, const float* __restrict__ Wfc,
          const float* __restrict__ Wrel, const float* __restrict__ Vb,
          const float* __restrict__ bv,
          short* __restrict__ Whi, short* __restrict__ Wlo,
          short* __restrict__ Wrh, short* __restrict__ Wrl,
          short* __restrict__ Vbh, short* __restrict__ Vbl,
          float* __restrict__ bcw)
{
    __shared__ float wfc[16 * 128];      // Wfc patch [16 d][128 ch]
    __shared__ float patch[16 * 257];    // fp32 result staging (A-path)
    const int tid = threadIdx.x;
    const int u = blockIdx.x;

    if (u < 64) {
        const bool isWc = (u < 32);
        const int t = isWc ? u : u - 32;
        const int g = t >> 4, dt = t & 15;
        const int gs = g * 128;
        // stage Wfc patch: rows dt*16..+16, cols gs..gs+128
        {
            int row = tid >> 4, ch8 = (tid & 15) * 8;
            const float* src = &Wfc[(long)(dt * 16 + row) * 256 + gs + ch8];
            float4 a = *(const float4*)src;
            float4 b = *(const float4*)(src + 4);
            float* d = &wfc[row * 128 + ch8];
            d[0] = a.x; d[1] = a.y; d[2] = a.z; d[3] = a.w;
            d[4] = b.x; d[5] = b.y; d[6] = b.z; d[7] = b.w;
        }
        __syncthreads();

        const int dl = tid >> 4, c16 = (tid & 15) * 16;
        float acc[16];
#pragma unroll
        for (int i = 0; i < 16; ++i) acc[i] = 0.f;

        if (isWc) {
            for (int ch = 0; ch < 128; ++ch) {
                float wf = wfc[dl * 128 + ch];
                const float* wr = &Wv[(long)(gs + ch) * 256 + c16];
                float4 a = *(const float4*)wr;
                float4 b = *(const float4*)(wr + 4);
                float4 c = *(const float4*)(wr + 8);
                float4 d4 = *(const float4*)(wr + 12);
                acc[0] += wf * a.x;  acc[1] += wf * a.y;
                acc[2] += wf * a.z;  acc[3] += wf * a.w;
                acc[4] += wf * b.x;  acc[5] += wf * b.y;
                acc[6] += wf * b.z;  acc[7] += wf * b.w;
                acc[8] += wf * c.x;  acc[9] += wf * c.y;
                acc[10] += wf * c.z; acc[11] += wf * c.w;
                acc[12] += wf * d4.x; acc[13] += wf * d4.y;
                acc[14] += wf * d4.z; acc[15] += wf * d4.w;
            }
            // stage for frag transpose
#pragma unroll
            for (int i = 0; i < 16; ++i) patch[dl * 257 + c16 + i] = acc[i];
            // bc for this d-tile
            if (tid < 16) {
                float s = 0.f;
                for (int ch = 0; ch < 128; ++ch)
                    s += wfc[tid * 128 + ch] * bv[gs + ch];
                bcw[g * 256 + dt * 16 + tid] = s;
            }
            __syncthreads();
            // A-frag conversion: 512 (kc,lane) units, 2 per thread
#pragma unroll
            for (int s2 = 0; s2 < 2; ++s2) {
                int idx = tid * 2 + s2;
                int kc = idx >> 6, lane = idx & 63;
                int n16 = lane & 15, quad = lane >> 4;
                short8 h8, l8;
#pragma unroll
                for (int j = 0; j < 8; ++j) {
                    float f = patch[n16 * 257 + kc * 32 + quad * 8 + j];
                    short hb = f2bf(f);
                    h8[j] = hb;
                    l8[j] = f2bf(f - bf2f(hb));
                }
                long off = (long)(2 + g) * 65536 + (((long)(dt * 8 + kc) * 64) + lane) * 8;
                *(short8*)(Whi + off) = h8;
                *(short8*)(Wlo + off) = l8;
            }
        } else {
            // Vb': D[d][w] over w16..w16+16 (w >= 225 -> 0)
            const int w16 = c16;
            for (int ch = 0; ch < 128; ++ch) {
                float wf = wfc[dl * 128 + ch];
                const float* vr = &Vb[(long)(gs + ch) * 225];
                if (w16 <= 208) {
#pragma unroll
                    for (int i = 0; i < 16; ++i) acc[i] += wf * vr[w16 + i];
                } else {
#pragma unroll
                    for (int i = 0; i < 16; ++i) {
                        int w = w16 + i;
                        float vv = 0.f;
                        if (w < 225) vv = vr[w];
                        acc[i] += wf * vv;
                    }
                }
            }
            // direct row-major store: row = g*256 + dt*16 + dl, cols w16..+16
            const long rb = (((long)(g * 256 + dt * 16 + dl)) << 8) + w16;
#pragma unroll
            for (int h = 0; h < 2; ++h) {
                short8 h8, l8;
#pragma unroll
                for (int j = 0; j < 8; ++j) {
                    float f = acc[h * 8 + j];
                    short hb = f2bf(f);
                    h8[j] = hb;
                    l8[j] = f2bf(f - bf2f(hb));
                }
                *(short8*)(Vbh + rb + h * 8) = h8;
                *(short8*)(Vbl + rb + h * 8) = l8;
            }
        }
    } else if (u < 128) {
        // Wq/Wk A-frags: 2 W x 16 dt x 2 kc-quads
        const int t = u - 64;
        const int w = t >> 5, rem = t & 31;
        const int dt = rem >> 1, kcq = (rem & 1) * 4;
        const int sub = tid >> 6, lane = tid & 63;
        const int kc = kcq + sub;
        const int n16 = lane & 15, quad = lane >> 4;
        const float* W = w ? Wk : Wq;
        const int d = dt * 16 + n16, cb = kc * 32 + quad * 8;
        float4 w0 = *(const float4*)&W[(long)d * 256 + cb];
        float4 w1 = *(const float4*)&W[(long)d * 256 + cb + 4];
        float f[8] = {w0.x, w0.y, w0.z, w0.w, w1.x, w1.y, w1.z, w1.w};
        short8 h8, l8;
#pragma unroll
        for (int j = 0; j < 8; ++j) {
            short hb = f2bf(f[j]);
            h8[j] = hb;
            l8[j] = f2bf(f[j] - bf2f(hb));
        }
        long off = (long)w * 65536 + (((long)(dt * 8 + kc) * 64) + lane) * 8;
        *(short8*)(Whi + off) = h8;
        *(short8*)(Wlo + off) = l8;
    } else {
        // Wrel frags
        const int t = u - 128;
        const int g = t / 15, wt = t - g * 15;
        const int kc = tid >> 6, lane = tid & 63;
        const int n16 = lane & 15, quad = lane >> 4;
        const int w = wt * 16 + n16;
        const int cb = kc * 32 + quad * 8;
        float f[8] = {0.f, 0.f, 0.f, 0.f, 0.f, 0.f, 0.f, 0.f};
        if (w < 225) {
            float4 w0 = *(const float4*)&Wrel[(long)(g * 225 + w) * 128 + cb];
            float4 w1 = *(const float4*)&Wrel[(long)(g * 225 + w) * 128 + cb + 4];
            f[0] = w0.x; f[1] = w0.y; f[2] = w0.z; f[3] = w0.w;
            f[4] = w1.x; f[5] = w1.y; f[6] = w1.z; f[7] = w1.w;
        }
        short8 h8, l8;
#pragma unroll
        for (int j = 0; j < 8; ++j) {
            short hb = f2bf(f[j]);
            h8[j] = hb;
            l8[j] = f2bf(f[j] - bf2f(hb));
        }
        long off = (long)g * 30720 + (((long)(wt * 4 + kc) * 64) + lane) * 8;
        *(short8*)(Wrh + off) = h8;
        *(short8*)(Wrl + off) = l8;
    }
}

// ---------------------------------------------------------------------------
// mfma_proj v7: grid (64 mt16, 16 z); sel = z>>2: 0=q, 1=k, 2=v'g0, 3=v'g1.
// A-frags pre-converted (prep). sel>=2 writes transposed 256-ch bf16 V'
// [batch*2+g][256 ch][32 y][48 x] with x-pads zeroed.
// ---------------------------------------------------------------------------
__global__ __launch_bounds__(256)
void mfma_proj(const float* __restrict__ q, const float* __restrict__ k,
               const float* __restrict__ v,
               const short* __restrict__ Whi, const short* __restrict__ Wlo,
               const float* __restrict__ bq, const float* __restrict__ bk,
               const float* __restrict__ bcw,
               short* __restrict__ qhi, short* __restrict__ qlo,
               short* __restrict__ khi, short* __restrict__ klo,
               short* __restrict__ vhi, short* __restrict__ vlo)
{
    __shared__ float st[256 * 17];       // staging [c 256][m 16 +1]; aliased as tile[16][257]
    const int tid = threadIdx.x;
    const int wave = tid >> 6, lane = tid & 63;
    const int n16 = lane & 15, quad = lane >> 4;
    const int mt16 = blockIdx.x, z = blockIdx.y;
    const int sel = z >> 2, batch = z & 3;

    const float* X = (sel == 0 ? q : sel == 1 ? k : v) + ((long)batch << 18);

    // ---- stage X tile: thread tid = channel c, 16 m's ----
    {
        const float* src = X + ((long)tid << 10) + mt16 * 16;
        float4 a0 = *(const float4*)(src);
        float4 a1 = *(const float4*)(src + 4);
        float4 a2 = *(const float4*)(src + 8);
        float4 a3 = *(const float4*)(src + 12);
        float* d = &st[tid * 17];
        d[0] = a0.x; d[1] = a0.y; d[2] = a0.z; d[3] = a0.w;
        d[4] = a1.x; d[5] = a1.y; d[6] = a1.z; d[7] = a1.w;
        d[8] = a2.x; d[9] = a2.y; d[10] = a2.z; d[11] = a2.w;
        d[12] = a3.x; d[13] = a3.y; d[14] = a3.z; d[15] = a3.w;
    }

    const float* bias = (sel == 0) ? bq : (sel == 1) ? bk : (bcw + (sel - 2) * 256);
    float bbv[4][4];
#pragma unroll
    for (int i = 0; i < 4; ++i) {
        float4 b4 = *(const float4*)&bias[(wave * 4 + i) * 16 + quad * 4];
        bbv[i][0] = b4.x; bbv[i][1] = b4.y; bbv[i][2] = b4.z; bbv[i][3] = b4.w;
    }
    __syncthreads();

    floatx4 acc[4] = {{0.f,0.f,0.f,0.f},{0.f,0.f,0.f,0.f},
                      {0.f,0.f,0.f,0.f},{0.f,0.f,0.f,0.f}};
    const long abase = (long)sel * 65536 + (long)lane * 8;
#pragma unroll
    for (int kc = 0; kc < 8; ++kc) {
        short8 bh, bl;
        const float* col = &st[(kc * 32 + quad * 8) * 17 + n16];
#pragma unroll
        for (int j = 0; j < 8; ++j) {
            float f = col[j * 17];
            short hb = f2bf(f);
            bh[j] = hb;
            bl[j] = f2bf(f - bf2f(hb));
        }
#pragma unroll
        for (int i = 0; i < 4; ++i) {
            const int dt = wave * 4 + i;
            short8 ahi = *(const short8*)(Whi + abase + (long)(dt * 8 + kc) * 512);
            short8 alo = *(const short8*)(Wlo + abase + (long)(dt * 8 + kc) * 512);
            acc[i] = __builtin_amdgcn_mfma_f32_16x16x32_bf16(ahi, bh, acc[i], 0, 0, 0);
            acc[i] = __builtin_amdgcn_mfma_f32_16x16x32_bf16(ahi, bl, acc[i], 0, 0, 0);
            acc[i] = __builtin_amdgcn_mfma_f32_16x16x32_bf16(alo, bh, acc[i], 0, 0, 0);
        }
    }

    // stage D[16 m][256 c] (alias st)
    __syncthreads();
    float* tile = st;
#pragma unroll
    for (int i = 0; i < 4; ++i) {
        const int dt = wave * 4 + i;
#pragma unroll
        for (int r = 0; r < 4; ++r)
            tile[n16 * 257 + dt * 16 + quad * 4 + r] = acc[i][r] + bbv[i][r];
    }
    __syncthreads();

    if (sel >= 2) {
        const int g = sel - 2;
        const int yq = mt16 >> 1, xb = (mt16 & 1) * 16;
        short8 h0, h1, l0, l1;
#pragma unroll
        for (int j = 0; j < 8; ++j) {
            float f0 = tile[j * 257 + tid];
            float f1 = tile[(j + 8) * 257 + tid];
            short hb0 = f2bf(f0), hb1 = f2bf(f1);
            h0[j] = hb0; l0[j] = f2bf(f0 - bf2f(hb0));
            h1[j] = hb1; l1[j] = f2bf(f1 - bf2f(hb1));
        }
        long o = ((long)((batch * 2 + g) * 256 + tid) * 32 + yq) * 48 + 8 + xb;
        *(short8*)(vhi + o) = h0;
        *(short8*)(vhi + o + 8) = h1;
        *(short8*)(vlo + o) = l0;
        *(short8*)(vlo + o + 8) = l1;
        // zero x-pads: (row = mt16>>1, side = mt16&1), all 256 ch
        const int prow = mt16 >> 1, side = mt16 & 1;
        long po = ((long)((batch * 2 + g) * 256 + tid) * 32 + prow) * 48 + side * 40;
        short8 zz = {0,0,0,0,0,0,0,0};
        *(short8*)(vhi + po) = zz;
        *(short8*)(vlo + po) = zz;
        return;
    }

    const float scale = (sel == 1) ? 0.08838834764831845f : 1.0f;
    const int m_l = tid >> 4, c16 = (tid & 15) * 16;
    const int m = mt16 * 16 + m_l;
    short* oh = sel ? khi : qhi;
    short* ol = sel ? klo : qlo;
#pragma unroll
    for (int half = 0; half < 2; ++half) {
        const int cg = c16 + half * 8;
        short8 h8, l8;
#pragma unroll
        for (int j = 0; j < 8; ++j) {
            float f = tile[m_l * 257 + cg + j] * scale;
            short hb = f2bf(f);
            h8[j] = hb;
            l8[j] = f2bf(f - bf2f(hb));
        }
        const int g = cg >> 7, ch = cg & 127;
        const long base = (((long)(batch * 2 + g) << 10) + m) * 128 + ch;
        *(short8*)(oh + base) = h8;
        *(short8*)(ol + base) = l8;
    }
}

// ---------------------------------------------------------------------------
// scores_pv (round-18): Wfc folded; writes final fp32 out via atomicAdd.
// grid 512 x 512 threads, XCD swizzle bz = lin&7.
// Phases: R rel; M mask; B band QK^T; softmax; T P->bf16;
// A bias GEMM (Vb'_g, 256 ch); V banded GEMM (V'_g, 256 ch);
// F: atomicAdd out (+bfc from g==0 block).
// ---------------------------------------------------------------------------
__global__ __launch_bounds__(512)
void scores_pv(const short* __restrict__ qhi, const short* __restrict__ qlo,
               const short* __restrict__ khi, const short* __restrict__ klo,
               const short* __restrict__ Wrh, const short* __restrict__ Wrl,
               const float* __restrict__ brel,
               const short* __restrict__ vhi, const short* __restrict__ vlo,
               const short* __restrict__ Vbh, const short* __restrict__ Vbl,
               const float* __restrict__ bfc, float* __restrict__ out)
{
    __shared__ __align__(16) float qk[16 * 241];   // 15.4 KB
    __shared__ __align__(16) short pah[16 * 264];  // 8.25 KB
    __shared__ __align__(16) short pal[16 * 264];  // 8.25 KB
    __shared__ float invl[16];

    const int tid = threadIdx.x;
    const int wave = tid >> 6, lane = tid & 63;     // wave 0..7
    const int lin = blockIdx.x;
    const int bz  = lin & 7;
    const int yy  = lin >> 3;
    const int y   = yy >> 1;
    const int xt  = yy & 1;
    const int g = bz & 1;
    const int x0 = xt * 16;

    const int n16 = lane & 15, quad = lane >> 4;
    const long qbase = (((long)bz << 10) + y * 32 + x0 + n16) * 128 + quad * 8;
    short8 a_hi[4], a_lo[4];
#pragma unroll
    for (int ch = 0; ch < 4; ++ch) {
        a_hi[ch] = *(const short8*)(qhi + qbase + ch * 32);
        a_lo[ch] = *(const short8*)(qlo + qbase + ch * 32);
    }

    // ---- phase R: rel logits (15 wt over 8 waves) ----
    for (int wt = wave; wt < 15; wt += 8) {
        const short* Ah = Wrh + (long)g * 30720 + ((long)(wt * 4) * 64 + lane) * 8;
        const short* Al = Wrl + (long)g * 30720 + ((long)(wt * 4) * 64 + lane) * 8;
        floatx4 racc = {0.f, 0.f, 0.f, 0.f};
#pragma unroll
        for (int kc = 0; kc < 4; ++kc) {
            short8 whh = *(const short8*)(Ah + kc * 512);
            short8 wll = *(const short8*)(Al + kc * 512);
            racc = __builtin_amdgcn_mfma_f32_16x16x32_bf16(whh, a_hi[kc], racc, 0, 0, 0);
            racc = __builtin_amdgcn_mfma_f32_16x16x32_bf16(whh, a_lo[kc], racc, 0, 0, 0);
            racc = __builtin_amdgcn_mfma_f32_16x16x32_bf16(wll, a_hi[kc], racc, 0, 0, 0);
        }
#pragma unroll
        for (int r = 0; r < 4; ++r) {
            int w = wt * 16 + quad * 4 + r;
            if (w < 225) {
                int dy = w / 15, dx = w - dy * 15;
                qk[n16 * 241 + dy * 16 + dx] = racc[r] + brel[g * 225 + w];
            }
        }
    }
    __syncthreads();

    // ---- phase M: mask invalid neighbors and pad slots ----
    for (int e = tid; e < 16 * 241; e += 512) {
        int px = e / 241, idx = e - px * 241;
        int dy = idx >> 4, dx = idx & 15;
        int hy = y + dy - 7, hx = x0 + px + dx - 7;
        bool valid = (dx < 15) && (dy < 15) &&
                     (hy >= 0) && (hy < 32) && (hx >= 0) && (hx < 32);
        if (!valid) qk[e] = -1e8f;
    }
    __syncthreads();

    // ---- phase B: band QK^T (15 dy over 8 waves) ----
    for (int dy = wave; dy < 15; dy += 8) {
        const int ky = y + dy - 7;
        if (ky < 0 || ky > 31) continue;
#pragma unroll
        for (int kxt = 0; kxt < 2; ++kxt) {
            const int kxg = x0 - 8 + kxt * 16 + n16;
            const long kb = (((long)bz << 10) + ky * 32 + kxg) * 128 + quad * 8;
            floatx4 acc = {0.f, 0.f, 0.f, 0.f};
#pragma unroll
            for (int ch = 0; ch < 4; ++ch) {
                short8 b_hi = *(const short8*)(khi + kb + ch * 32);
                short8 b_lo = *(const short8*)(klo + kb + ch * 32);
                acc = __builtin_amdgcn_mfma_f32_16x16x32_bf16(a_hi[ch], b_hi, acc, 0, 0, 0);
                acc = __builtin_amdgcn_mfma_f32_16x16x32_bf16(a_hi[ch], b_lo, acc, 0, 0, 0);
                acc = __builtin_amdgcn_mfma_f32_16x16x32_bf16(a_lo[ch], b_hi, acc, 0, 0, 0);
            }
            if (kxg >= 0 && kxg < 32) {
#pragma unroll
                for (int r = 0; r < 4; ++r) {
                    int m = quad * 4 + r;
                    int dx = kxg - (x0 + m) + 7;
                    if (dx >= 0 && dx < 15) {
                        int s = m * 241 + dy * 16 + dx;
                        qk[s] = qk[s] + acc[r];
                    }
                }
            }
        }
    }
    __syncthreads();

    // ---- softmax: 32 lanes per px row ----
    {
        int px = tid >> 5, s = tid & 31;
        float mx = -3.0e38f;
        for (int w = s; w < 240; w += 32) mx = fmaxf(mx, qk[px * 241 + w]);
#pragma unroll
        for (int msk = 16; msk; msk >>= 1) mx = fmaxf(mx, __shfl_xor(mx, msk));
        float sum = 0.f;
        for (int w = s; w < 240; w += 32) {
            float p = __expf(qk[px * 241 + w] - mx);
            qk[px * 241 + w] = p;
            sum += p;
        }
#pragma unroll
        for (int msk = 16; msk; msk >>= 1) sum += __shfl_xor(sum, msk);
        if (s == 0) invl[px] = 1.0f / sum;
    }
    __syncthreads();

    // ---- phase T: normalize + bf16 hi/lo into pah/pal (w >= 225 -> 0) ----
    for (int e = tid; e < 4096; e += 512) {
        int px = e >> 8, w = e & 255;
        float p = 0.f;
        if (w < 225) {
            int dy2 = w / 15, dx2 = w - dy2 * 15;
            p = qk[px * 241 + dy2 * 16 + dx2] * invl[px];
        }
        short hb = f2bf(p);
        pah[px * 264 + w] = hb;
        pal[px * 264 + w] = f2bf(p - bf2f(hb));
    }
    __syncthreads();

    // ---- phases A+V: MFMA accumulation, 2 ch-tiles per wave (256 d) ----
    floatx4 acc[2] = {{0.f,0.f,0.f,0.f},{0.f,0.f,0.f,0.f}};
    const int ch0a = wave * 32;
    const int ch0b = wave * 32 + 16;

    // (A) bias GEMM: P[16 x 225] x Vb'_g[225 x 256], 8 k-chunks of 32
#pragma unroll
    for (int wk = 0; wk < 8; ++wk) {
        short8 pa_h = *(const short8*)&pah[n16 * 264 + wk * 32 + quad * 8];
        short8 pa_l = *(const short8*)&pal[n16 * 264 + wk * 32 + quad * 8];
        const long vb0 = (((long)(g * 256 + ch0a + n16)) << 8) + wk * 32 + quad * 8;
        const long vb1 = (((long)(g * 256 + ch0b + n16)) << 8) + wk * 32 + quad * 8;
        short8 b0h = *(const short8*)(Vbh + vb0);
        short8 b0l = *(const short8*)(Vbl + vb0);
        short8 b1h = *(const short8*)(Vbh + vb1);
        short8 b1l = *(const short8*)(Vbl + vb1);
        acc[0] = __builtin_amdgcn_mfma_f32_16x16x32_bf16(pa_h, b0h, acc[0], 0, 0, 0);
        acc[0] = __builtin_amdgcn_mfma_f32_16x16x32_bf16(pa_h, b0l, acc[0], 0, 0, 0);
        acc[0] = __builtin_amdgcn_mfma_f32_16x16x32_bf16(pa_l, b0h, acc[0], 0, 0, 0);
        acc[1] = __builtin_amdgcn_mfma_f32_16x16x32_bf16(pa_h, b1h, acc[1], 0, 0, 0);
        acc[1] = __builtin_amdgcn_mfma_f32_16x16x32_bf16(pa_h, b1l, acc[1], 0, 0, 0);
        acc[1] = __builtin_amdgcn_mfma_f32_16x16x32_bf16(pa_l, b1h, acc[1], 0, 0, 0);
    }

    // (V) banded GEMM per dy over V'_g (256 ch)
    for (int dy = 0; dy < 15; ++dy) {
        const int ky = y + dy - 7;
        if (ky < 0 || ky > 31) continue;
        short8 bnd_h, bnd_l;
        const int rowoff = n16 * 264 + dy * 15 - n16 - 1;
#pragma unroll
        for (int j = 0; j < 8; ++j) {
            int kk = quad * 8 + j;
            int dx = kk - n16 - 1;
            bool valid = (unsigned)dx < 15u;
            int idx = valid ? (rowoff + kk) : 0;
            short vh = pah[idx];
            short vl = pal[idx];
            bnd_h[j] = valid ? vh : (short)0;
            bnd_l[j] = valid ? vl : (short)0;
        }
        const long v0o = (((long)(bz * 256 + ch0a + n16)) * 32 + ky) * 48 + x0 + quad * 8;
        const long v1o = (((long)(bz * 256 + ch0b + n16)) * 32 + ky) * 48 + x0 + quad * 8;
        short8 v0h = *(const short8*)(vhi + v0o);
        short8 v0l = *(const short8*)(vlo + v0o);
        short8 v1h = *(const short8*)(vhi + v1o);
        short8 v1l = *(const short8*)(vlo + v1o);
        acc[0] = __builtin_amdgcn_mfma_f32_16x16x32_bf16(bnd_h, v0h, acc[0], 0, 0, 0);
        acc[0] = __builtin_amdgcn_mfma_f32_16x16x32_bf16(bnd_h, v0l, acc[0], 0, 0, 0);
        acc[0] = __builtin_amdgcn_mfma_f32_16x16x32_bf16(bnd_l, v0h, acc[0], 0, 0, 0);
        acc[1] = __builtin_amdgcn_mfma_f32_16x16x32_bf16(bnd_h, v1h, acc[1], 0, 0, 0);
        acc[1] = __builtin_amdgcn_mfma_f32_16x16x32_bf16(bnd_h, v1l, acc[1], 0, 0, 0);
        acc[1] = __builtin_amdgcn_mfma_f32_16x16x32_bf16(bnd_l, v1h, acc[1], 0, 0, 0);
    }

    // ---- phase F: atomicAdd final output (g==0 adds bfc) ----
    const int n = bz >> 1;
#pragma unroll
    for (int t = 0; t < 2; ++t) {
        const int d = (t ? ch0b : ch0a) + n16;
        const float badd = (g == 0) ? bfc[d] : 0.f;
#pragma unroll
        for (int r = 0; r < 4; ++r) {
            const int px = quad * 4 + r;
            long o = ((long)(y * 32 + x0 + px) * 4 + n) * 256 + d;
            atomicAdd(&out[o], acc[t][r] + badd);
        }
    }
}

// ---------------------------------------------------------------------------
// ws floats:
//   vhi@2097152 len 1572864 | vlo@3670016 len 1572864
//   Vbh@5242880 len 65536   | Vbl@5308416 len 65536 | bcw@5373952 len 512
//   qhi@6561792 qlo@7086080 khi@7610368 klo@8134656 (524288 each)
//   Whi@11804672 len 131072 (4 sels) | Wlo@11935744 len 131072
//   Wrh@13115392 len 30720 | Wrl@13146112 len 30720
// ---------------------------------------------------------------------------
extern "C" void kernel_launch(void* const* d_in, const int* in_sizes, int n_in,
                              void* d_out, int out_size, void* d_ws, size_t ws_size,
                              hipStream_t stream)
{
    const float* q    = (const float*)d_in[0];
    const float* k    = (const float*)d_in[1];
    const float* v    = (const float*)d_in[2];
    const float* Wq   = (const float*)d_in[3];
    const float* bq   = (const float*)d_in[4];
    const float* Wk   = (const float*)d_in[5];
    const float* bk   = (const float*)d_in[6];
    const float* Wv   = (const float*)d_in[7];
    const float* bv   = (const float*)d_in[8];
    const float* Wrel = (const float*)d_in[9];
    const float* brel = (const float*)d_in[10];
    const float* Vb   = (const float*)d_in[11];
    const float* Wfc  = (const float*)d_in[12];
    const float* bfc  = (const float*)d_in[13];
    float* out = (float*)d_out;

    float* ws   = (float*)d_ws;
    short* vhi  = (short*)(ws + 2097152);
    short* vlo  = (short*)(ws + 3670016);
    short* Vbh  = (short*)(ws + 5242880);
    short* Vbl  = (short*)(ws + 5308416);
    float* bcw  = ws + 5373952;
    short* qhi  = (short*)(ws + 6561792);
    short* qlo  = (short*)(ws + 7086080);
    short* khi  = (short*)(ws + 7610368);
    short* klo  = (short*)(ws + 8134656);
    short* Whi  = (short*)(ws + 11804672);
    short* Wlo  = (short*)(ws + 11935744);
    short* Wrh  = (short*)(ws + 13115392);
    short* Wrl  = (short*)(ws + 13146112);

    // out accumulates atomically -> zero first
    hipMemsetAsync(d_out, 0, out_size, stream);

    // weight-side prep: Wc/bc GEMMs, Vb' GEMM, Wq/Wk/Wrel frags
    prep<<<dim3(158), dim3(256), 0, stream>>>(Wq, Wk, Wv, Wfc, Wrel, Vb, bv,
                                              Whi, Wlo, Wrh, Wrl, Vbh, Vbl, bcw);

    // projections q, k, v'g0, v'g1: 1024 blocks
    mfma_proj<<<dim3(64, 16), dim3(256), 0, stream>>>(q, k, v, Whi, Wlo,
                                                      bq, bk, bcw,
                                                      qhi, qlo, khi, klo,
                                                      vhi, vlo);

    // scores + softmax + folded PV -> final out (atomic): 512 x 512
    scores_pv<<<dim3(512), dim3(512), 0, stream>>>(qhi, qlo, khi, klo,
                                                   Wrh, Wrl, brel,
                                                   vhi, vlo, Vbh, Vbl,
                                                   bfc, out);
}

// Round 9
// 194.998 us; speedup vs baseline: 1.3442x; 1.3442x over previous
//
#include <hip/hip_runtime.h>
#include <math.h>

// N=4, C=256, H=W=32, NH=2, HD=128, MAX_DIS=7, WS=15, WW=225, T=sqrt(128)
// out: [hw=1024][n=4][c=256] fp32
//
// Wfc folded backward through PV:
//   Wc_g  = Wfc[:,g*128:+128] @ Wv[g*128:+128,:]   (256x256 per head)
//   bc_g  = Wfc[:,gs] @ bv[gs]                      (256 per head)
//   Vb'_g = Wfc[:,gs] @ Vb[g]                       (256 x 225 per head)
//   out[m,n,:] = sum_g P_g . (V'_g_un + Vb'_g) + bfc,  V'_g = Wc_g x + bc_g

typedef __attribute__((ext_vector_type(8))) short short8;
typedef __attribute__((ext_vector_type(4))) float floatx4;

__device__ __forceinline__ short f2bf(float f) {
    unsigned u = __float_as_uint(f);
    unsigned r = (u + 0x7fffu + ((u >> 16) & 1u)) >> 16;
    return (short)r;
}
__device__ __forceinline__ float bf2f(short s) {
    return __uint_as_float(((unsigned)(unsigned short)s) << 16);
}

// ---------------------------------------------------------------------------
// prep v2: weight-side work, LDS-tiled fp32 GEMMs (round-8 prep was a
// 128-iter unstaged-global-load serial loop -> 109 us; this stages through
// LDS with coalesced float4 loads, identical fp32 accumulation order).
// grid 158 x 256:
//  u [0,32)   : Wc_g tile 64x64 (k=128, 4 chunks) -> A-frags sel 2+g; bc_g.
//  u [32,64)  : Vb'_g tile 64x64 -> row-major hi/lo (Vbh/Vbl).
//  u [64,128) : Wq/Wk A-frags.
//  u [128,158): Wrel frags.
// ---------------------------------------------------------------------------
__global__ __launch_bounds__(256)
void prep(const float* __restrict__ Wq, const float* __restrict__ Wk,
          const float* __restrict__ Wv, const float* __restrict__ Wfc,
          const float* __restrict__ Wrel, const float* __restrict__ Vb,
          const float* __restrict__ bv,
          short* __restrict__ Whi, short* __restrict__ Wlo,
          short* __restrict__ Wrh, short* __restrict__ Wrl,
          short* __restrict__ Vbh, short* __restrict__ Vbl,
          float* __restrict__ bcw)
{
    __shared__ float smem[64 * 33 + 32 * 65];   // As[64][33] | Bs[32][65]; Os[64][65] aliases
    const int tid = threadIdx.x;
    const int u = blockIdx.x;

    if (u < 64) {
        const bool isWc = (u < 32);
        const int t = u & 31;
        const int g = t >> 4;          // head
        const int ty = (t >> 2) & 3;   // output row tile
        const int tx = t & 3;          // output col tile
        const int gs = g * 128;
        const int d0 = ty * 64, c0 = tx * 64;

        float* As = smem;              // [64][33]
        float* Bs = smem + 64 * 33;    // [32][65]

        float acc[4][4];
#pragma unroll
        for (int i = 0; i < 4; ++i)
#pragma unroll
            for (int j = 0; j < 4; ++j) acc[i][j] = 0.f;
        float bcacc = 0.f;

        const int tyl = tid >> 4, txl = tid & 15;

        for (int kk = 0; kk < 128; kk += 32) {
            // stage A: Wfc[d0..+64][gs+kk..+32]
            {
                int row = tid >> 2, c8 = (tid & 3) * 8;
                const float* src = &Wfc[(long)(d0 + row) * 256 + gs + kk + c8];
                float4 a = *(const float4*)src;
                float4 b = *(const float4*)(src + 4);
                float* d = &As[row * 33 + c8];
                d[0] = a.x; d[1] = a.y; d[2] = a.z; d[3] = a.w;
                d[4] = b.x; d[5] = b.y; d[6] = b.z; d[7] = b.w;
            }
            // stage B: Wv[gs+kk..+32][c0..+64]  or  Vb[g][gs-rel ch][w] (w>=225 -> 0)
            {
                int row = tid >> 3, c8 = (tid & 7) * 8;
                float* d = &Bs[row * 65 + c8];
                if (isWc) {
                    const float* src = &Wv[(long)(gs + kk + row) * 256 + c0 + c8];
                    float4 a = *(const float4*)src;
                    float4 b = *(const float4*)(src + 4);
                    d[0] = a.x; d[1] = a.y; d[2] = a.z; d[3] = a.w;
                    d[4] = b.x; d[5] = b.y; d[6] = b.z; d[7] = b.w;
                } else {
                    const float* vr = &Vb[(long)(gs + kk + row) * 225];
#pragma unroll
                    for (int j = 0; j < 8; ++j) {
                        int w = c0 + c8 + j;
                        d[j] = (w < 225) ? vr[w] : 0.f;
                    }
                }
            }
            __syncthreads();

            // bc partial (Wc path, col-tile 0 only): As holds Wfc[64][32]
            if (isWc && tx == 0 && tid < 64) {
#pragma unroll
                for (int k = 0; k < 32; ++k)
                    bcacc += As[tid * 33 + k] * bv[gs + kk + k];
            }

#pragma unroll
            for (int k = 0; k < 32; ++k) {
                float a0 = As[(tyl * 4 + 0) * 33 + k];
                float a1 = As[(tyl * 4 + 1) * 33 + k];
                float a2 = As[(tyl * 4 + 2) * 33 + k];
                float a3 = As[(tyl * 4 + 3) * 33 + k];
                float b0 = Bs[k * 65 + txl * 4 + 0];
                float b1 = Bs[k * 65 + txl * 4 + 1];
                float b2 = Bs[k * 65 + txl * 4 + 2];
                float b3 = Bs[k * 65 + txl * 4 + 3];
                acc[0][0] += a0 * b0; acc[0][1] += a0 * b1;
                acc[0][2] += a0 * b2; acc[0][3] += a0 * b3;
                acc[1][0] += a1 * b0; acc[1][1] += a1 * b1;
                acc[1][2] += a1 * b2; acc[1][3] += a1 * b3;
                acc[2][0] += a2 * b0; acc[2][1] += a2 * b1;
                acc[2][2] += a2 * b2; acc[2][3] += a2 * b3;
                acc[3][0] += a3 * b0; acc[3][1] += a3 * b1;
                acc[3][2] += a3 * b2; acc[3][3] += a3 * b3;
            }
            __syncthreads();
        }

        if (isWc && tx == 0 && tid < 64)
            bcw[g * 256 + d0 + tid] = bcacc;

        // stage fp32 result to Os[64][65] (aliases As/Bs; barrier above done)
        float* Os = smem;
#pragma unroll
        for (int i = 0; i < 4; ++i)
#pragma unroll
            for (int j = 0; j < 4; ++j)
                Os[(tyl * 4 + i) * 65 + txl * 4 + j] = acc[i][j];
        __syncthreads();

        if (isWc) {
            // A-frag conversion: 4 dtl x 2 kcl x 64 lanes = 512 units, 2/thread
#pragma unroll
            for (int s2 = 0; s2 < 2; ++s2) {
                int idx = tid * 2 + s2;
                int dtl = idx >> 7, rem = idx & 127;
                int kcl = rem >> 6, lane = rem & 63;
                int n16 = lane & 15, quad = lane >> 4;
                short8 h8, l8;
#pragma unroll
                for (int j = 0; j < 8; ++j) {
                    float f = Os[(dtl * 16 + n16) * 65 + kcl * 32 + quad * 8 + j];
                    short hb = f2bf(f);
                    h8[j] = hb;
                    l8[j] = f2bf(f - bf2f(hb));
                }
                int dt = (d0 >> 4) + dtl, kc = (c0 >> 5) + kcl;
                long off = (long)(2 + g) * 65536 + (((long)(dt * 8 + kc) * 64) + lane) * 8;
                *(short8*)(Whi + off) = h8;
                *(short8*)(Wlo + off) = l8;
            }
        } else {
            // row-major hi/lo store: 64 rows x 8 col-segs = 512 units, 2/thread
#pragma unroll
            for (int s2 = 0; s2 < 2; ++s2) {
                int idx = tid * 2 + s2;
                int row = idx >> 3, c8 = (idx & 7) * 8;
                short8 h8, l8;
#pragma unroll
                for (int j = 0; j < 8; ++j) {
                    float f = Os[row * 65 + c8 + j];
                    short hb = f2bf(f);
                    h8[j] = hb;
                    l8[j] = f2bf(f - bf2f(hb));
                }
                long rb = (((long)(g * 256 + d0 + row)) << 8) + c0 + c8;
                *(short8*)(Vbh + rb) = h8;
                *(short8*)(Vbl + rb) = l8;
            }
        }
    } else if (u < 128) {
        // Wq/Wk A-frags: 2 W x 16 dt x 2 kc-quads
        const int t = u - 64;
        const int w = t >> 5, rem = t & 31;
        const int dt = rem >> 1, kcq = (rem & 1) * 4;
        const int sub = tid >> 6, lane = tid & 63;
        const int kc = kcq + sub;
        const int n16 = lane & 15, quad = lane >> 4;
        const float* W = w ? Wk : Wq;
        const int d = dt * 16 + n16, cb = kc * 32 + quad * 8;
        float4 w0 = *(const float4*)&W[(long)d * 256 + cb];
        float4 w1 = *(const float4*)&W[(long)d * 256 + cb + 4];
        float f[8] = {w0.x, w0.y, w0.z, w0.w, w1.x, w1.y, w1.z, w1.w};
        short8 h8, l8;
#pragma unroll
        for (int j = 0; j < 8; ++j) {
            short hb = f2bf(f[j]);
            h8[j] = hb;
            l8[j] = f2bf(f[j] - bf2f(hb));
        }
        long off = (long)w * 65536 + (((long)(dt * 8 + kc) * 64) + lane) * 8;
        *(short8*)(Whi + off) = h8;
        *(short8*)(Wlo + off) = l8;
    } else {
        // Wrel frags
        const int t = u - 128;
        const int g = t / 15, wt = t - g * 15;
        const int kc = tid >> 6, lane = tid & 63;
        const int n16 = lane & 15, quad = lane >> 4;
        const int w = wt * 16 + n16;
        const int cb = kc * 32 + quad * 8;
        float f[8] = {0.f, 0.f, 0.f, 0.f, 0.f, 0.f, 0.f, 0.f};
        if (w < 225) {
            float4 w0 = *(const float4*)&Wrel[(long)(g * 225 + w) * 128 + cb];
            float4 w1 = *(const float4*)&Wrel[(long)(g * 225 + w) * 128 + cb + 4];
            f[0] = w0.x; f[1] = w0.y; f[2] = w0.z; f[3] = w0.w;
            f[4] = w1.x; f[5] = w1.y; f[6] = w1.z; f[7] = w1.w;
        }
        short8 h8, l8;
#pragma unroll
        for (int j = 0; j < 8; ++j) {
            short hb = f2bf(f[j]);
            h8[j] = hb;
            l8[j] = f2bf(f[j] - bf2f(hb));
        }
        long off = (long)g * 30720 + (((long)(wt * 4 + kc) * 64) + lane) * 8;
        *(short8*)(Wrh + off) = h8;
        *(short8*)(Wrl + off) = l8;
    }
}

// ---------------------------------------------------------------------------
// mfma_proj v7 (unchanged from round 8): grid (64 mt16, 16 z);
// sel = z>>2: 0=q, 1=k, 2=v'g0, 3=v'g1. A-frags pre-converted (prep).
// sel>=2 writes transposed 256-ch bf16 V' [batch*2+g][256][32 y][48 x].
// ---------------------------------------------------------------------------
__global__ __launch_bounds__(256)
void mfma_proj(const float* __restrict__ q, const float* __restrict__ k,
               const float* __restrict__ v,
               const short* __restrict__ Whi, const short* __restrict__ Wlo,
               const float* __restrict__ bq, const float* __restrict__ bk,
               const float* __restrict__ bcw,
               short* __restrict__ qhi, short* __restrict__ qlo,
               short* __restrict__ khi, short* __restrict__ klo,
               short* __restrict__ vhi, short* __restrict__ vlo)
{
    __shared__ float st[256 * 17];       // staging [c 256][m 16 +1]; aliased as tile[16][257]
    const int tid = threadIdx.x;
    const int wave = tid >> 6, lane = tid & 63;
    const int n16 = lane & 15, quad = lane >> 4;
    const int mt16 = blockIdx.x, z = blockIdx.y;
    const int sel = z >> 2, batch = z & 3;

    const float* X = (sel == 0 ? q : sel == 1 ? k : v) + ((long)batch << 18);

    // ---- stage X tile: thread tid = channel c, 16 m's ----
    {
        const float* src = X + ((long)tid << 10) + mt16 * 16;
        float4 a0 = *(const float4*)(src);
        float4 a1 = *(const float4*)(src + 4);
        float4 a2 = *(const float4*)(src + 8);
        float4 a3 = *(const float4*)(src + 12);
        float* d = &st[tid * 17];
        d[0] = a0.x; d[1] = a0.y; d[2] = a0.z; d[3] = a0.w;
        d[4] = a1.x; d[5] = a1.y; d[6] = a1.z; d[7] = a1.w;
        d[8] = a2.x; d[9] = a2.y; d[10] = a2.z; d[11] = a2.w;
        d[12] = a3.x; d[13] = a3.y; d[14] = a3.z; d[15] = a3.w;
    }

    const float* bias = (sel == 0) ? bq : (sel == 1) ? bk : (bcw + (sel - 2) * 256);
    float bbv[4][4];
#pragma unroll
    for (int i = 0; i < 4; ++i) {
        float4 b4 = *(const float4*)&bias[(wave * 4 + i) * 16 + quad * 4];
        bbv[i][0] = b4.x; bbv[i][1] = b4.y; bbv[i][2] = b4.z; bbv[i][3] = b4.w;
    }
    __syncthreads();

    floatx4 acc[4] = {{0.f,0.f,0.f,0.f},{0.f,0.f,0.f,0.f},
                      {0.f,0.f,0.f,0.f},{0.f,0.f,0.f,0.f}};
    const long abase = (long)sel * 65536 + (long)lane * 8;
#pragma unroll
    for (int kc = 0; kc < 8; ++kc) {
        short8 bh, bl;
        const float* col = &st[(kc * 32 + quad * 8) * 17 + n16];
#pragma unroll
        for (int j = 0; j < 8; ++j) {
            float f = col[j * 17];
            short hb = f2bf(f);
            bh[j] = hb;
            bl[j] = f2bf(f - bf2f(hb));
        }
#pragma unroll
        for (int i = 0; i < 4; ++i) {
            const int dt = wave * 4 + i;
            short8 ahi = *(const short8*)(Whi + abase + (long)(dt * 8 + kc) * 512);
            short8 alo = *(const short8*)(Wlo + abase + (long)(dt * 8 + kc) * 512);
            acc[i] = __builtin_amdgcn_mfma_f32_16x16x32_bf16(ahi, bh, acc[i], 0, 0, 0);
            acc[i] = __builtin_amdgcn_mfma_f32_16x16x32_bf16(ahi, bl, acc[i], 0, 0, 0);
            acc[i] = __builtin_amdgcn_mfma_f32_16x16x32_bf16(alo, bh, acc[i], 0, 0, 0);
        }
    }

    // stage D[16 m][256 c] (alias st)
    __syncthreads();
    float* tile = st;
#pragma unroll
    for (int i = 0; i < 4; ++i) {
        const int dt = wave * 4 + i;
#pragma unroll
        for (int r = 0; r < 4; ++r)
            tile[n16 * 257 + dt * 16 + quad * 4 + r] = acc[i][r] + bbv[i][r];
    }
    __syncthreads();

    if (sel >= 2) {
        const int g = sel - 2;
        const int yq = mt16 >> 1, xb = (mt16 & 1) * 16;
        short8 h0, h1, l0, l1;
#pragma unroll
        for (int j = 0; j < 8; ++j) {
            float f0 = tile[j * 257 + tid];
            float f1 = tile[(j + 8) * 257 + tid];
            short hb0 = f2bf(f0), hb1 = f2bf(f1);
            h0[j] = hb0; l0[j] = f2bf(f0 - bf2f(hb0));
            h1[j] = hb1; l1[j] = f2bf(f1 - bf2f(hb1));
        }
        long o = ((long)((batch * 2 + g) * 256 + tid) * 32 + yq) * 48 + 8 + xb;
        *(short8*)(vhi + o) = h0;
        *(short8*)(vhi + o + 8) = h1;
        *(short8*)(vlo + o) = l0;
        *(short8*)(vlo + o + 8) = l1;
        // zero x-pads: (row = mt16>>1, side = mt16&1), all 256 ch
        const int prow = mt16 >> 1, side = mt16 & 1;
        long po = ((long)((batch * 2 + g) * 256 + tid) * 32 + prow) * 48 + side * 40;
        short8 zz = {0,0,0,0,0,0,0,0};
        *(short8*)(vhi + po) = zz;
        *(short8*)(vlo + po) = zz;
        return;
    }

    const float scale = (sel == 1) ? 0.08838834764831845f : 1.0f;
    const int m_l = tid >> 4, c16 = (tid & 15) * 16;
    const int m = mt16 * 16 + m_l;
    short* oh = sel ? khi : qhi;
    short* ol = sel ? klo : qlo;
#pragma unroll
    for (int half = 0; half < 2; ++half) {
        const int cg = c16 + half * 8;
        short8 h8, l8;
#pragma unroll
        for (int j = 0; j < 8; ++j) {
            float f = tile[m_l * 257 + cg + j] * scale;
            short hb = f2bf(f);
            h8[j] = hb;
            l8[j] = f2bf(f - bf2f(hb));
        }
        const int g = cg >> 7, ch = cg & 127;
        const long base = (((long)(batch * 2 + g) << 10) + m) * 128 + ch;
        *(short8*)(oh + base) = h8;
        *(short8*)(ol + base) = l8;
    }
}

// ---------------------------------------------------------------------------
// scores_pv (unchanged from round 8): Wfc folded; atomicAdd fp32 out.
// grid 512 x 512 threads, XCD swizzle bz = lin&7.
// ---------------------------------------------------------------------------
__global__ __launch_bounds__(512)
void scores_pv(const short* __restrict__ qhi, const short* __restrict__ qlo,
               const short* __restrict__ khi, const short* __restrict__ klo,
               const short* __restrict__ Wrh, const short* __restrict__ Wrl,
               const float* __restrict__ brel,
               const short* __restrict__ vhi, const short* __restrict__ vlo,
               const short* __restrict__ Vbh, const short* __restrict__ Vbl,
               const float* __restrict__ bfc, float* __restrict__ out)
{
    __shared__ __align__(16) float qk[16 * 241];   // 15.4 KB
    __shared__ __align__(16) short pah[16 * 264];  // 8.25 KB
    __shared__ __align__(16) short pal[16 * 264];  // 8.25 KB
    __shared__ float invl[16];

    const int tid = threadIdx.x;
    const int wave = tid >> 6, lane = tid & 63;     // wave 0..7
    const int lin = blockIdx.x;
    const int bz  = lin & 7;
    const int yy  = lin >> 3;
    const int y   = yy >> 1;
    const int xt  = yy & 1;
    const int g = bz & 1;
    const int x0 = xt * 16;

    const int n16 = lane & 15, quad = lane >> 4;
    const long qbase = (((long)bz << 10) + y * 32 + x0 + n16) * 128 + quad * 8;
    short8 a_hi[4], a_lo[4];
#pragma unroll
    for (int ch = 0; ch < 4; ++ch) {
        a_hi[ch] = *(const short8*)(qhi + qbase + ch * 32);
        a_lo[ch] = *(const short8*)(qlo + qbase + ch * 32);
    }

    // ---- phase R: rel logits (15 wt over 8 waves) ----
    for (int wt = wave; wt < 15; wt += 8) {
        const short* Ah = Wrh + (long)g * 30720 + ((long)(wt * 4) * 64 + lane) * 8;
        const short* Al = Wrl + (long)g * 30720 + ((long)(wt * 4) * 64 + lane) * 8;
        floatx4 racc = {0.f, 0.f, 0.f, 0.f};
#pragma unroll
        for (int kc = 0; kc < 4; ++kc) {
            short8 whh = *(const short8*)(Ah + kc * 512);
            short8 wll = *(const short8*)(Al + kc * 512);
            racc = __builtin_amdgcn_mfma_f32_16x16x32_bf16(whh, a_hi[kc], racc, 0, 0, 0);
            racc = __builtin_amdgcn_mfma_f32_16x16x32_bf16(whh, a_lo[kc], racc, 0, 0, 0);
            racc = __builtin_amdgcn_mfma_f32_16x16x32_bf16(wll, a_hi[kc], racc, 0, 0, 0);
        }
#pragma unroll
        for (int r = 0; r < 4; ++r) {
            int w = wt * 16 + quad * 4 + r;
            if (w < 225) {
                int dy = w / 15, dx = w - dy * 15;
                qk[n16 * 241 + dy * 16 + dx] = racc[r] + brel[g * 225 + w];
            }
        }
    }
    __syncthreads();

    // ---- phase M: mask invalid neighbors and pad slots ----
    for (int e = tid; e < 16 * 241; e += 512) {
        int px = e / 241, idx = e - px * 241;
        int dy = idx >> 4, dx = idx & 15;
        int hy = y + dy - 7, hx = x0 + px + dx - 7;
        bool valid = (dx < 15) && (dy < 15) &&
                     (hy >= 0) && (hy < 32) && (hx >= 0) && (hx < 32);
        if (!valid) qk[e] = -1e8f;
    }
    __syncthreads();

    // ---- phase B: band QK^T (15 dy over 8 waves) ----
    for (int dy = wave; dy < 15; dy += 8) {
        const int ky = y + dy - 7;
        if (ky < 0 || ky > 31) continue;
#pragma unroll
        for (int kxt = 0; kxt < 2; ++kxt) {
            const int kxg = x0 - 8 + kxt * 16 + n16;
            const long kb = (((long)bz << 10) + ky * 32 + kxg) * 128 + quad * 8;
            floatx4 acc = {0.f, 0.f, 0.f, 0.f};
#pragma unroll
            for (int ch = 0; ch < 4; ++ch) {
                short8 b_hi = *(const short8*)(khi + kb + ch * 32);
                short8 b_lo = *(const short8*)(klo + kb + ch * 32);
                acc = __builtin_amdgcn_mfma_f32_16x16x32_bf16(a_hi[ch], b_hi, acc, 0, 0, 0);
                acc = __builtin_amdgcn_mfma_f32_16x16x32_bf16(a_hi[ch], b_lo, acc, 0, 0, 0);
                acc = __builtin_amdgcn_mfma_f32_16x16x32_bf16(a_lo[ch], b_hi, acc, 0, 0, 0);
            }
            if (kxg >= 0 && kxg < 32) {
#pragma unroll
                for (int r = 0; r < 4; ++r) {
                    int m = quad * 4 + r;
                    int dx = kxg - (x0 + m) + 7;
                    if (dx >= 0 && dx < 15) {
                        int s = m * 241 + dy * 16 + dx;
                        qk[s] = qk[s] + acc[r];
                    }
                }
            }
        }
    }
    __syncthreads();

    // ---- softmax: 32 lanes per px row ----
    {
        int px = tid >> 5, s = tid & 31;
        float mx = -3.0e38f;
        for (int w = s; w < 240; w += 32) mx = fmaxf(mx, qk[px * 241 + w]);
#pragma unroll
        for (int msk = 16; msk; msk >>= 1) mx = fmaxf(mx, __shfl_xor(mx, msk));
        float sum = 0.f;
        for (int w = s; w < 240; w += 32) {
            float p = __expf(qk[px * 241 + w] - mx);
            qk[px * 241 + w] = p;
            sum += p;
        }
#pragma unroll
        for (int msk = 16; msk; msk >>= 1) sum += __shfl_xor(sum, msk);
        if (s == 0) invl[px] = 1.0f / sum;
    }
    __syncthreads();

    // ---- phase T: normalize + bf16 hi/lo into pah/pal (w >= 225 -> 0) ----
    for (int e = tid; e < 4096; e += 512) {
        int px = e >> 8, w = e & 255;
        float p = 0.f;
        if (w < 225) {
            int dy2 = w / 15, dx2 = w - dy2 * 15;
            p = qk[px * 241 + dy2 * 16 + dx2] * invl[px];
        }
        short hb = f2bf(p);
        pah[px * 264 + w] = hb;
        pal[px * 264 + w] = f2bf(p - bf2f(hb));
    }
    __syncthreads();

    // ---- phases A+V: MFMA accumulation, 2 ch-tiles per wave (256 d) ----
    floatx4 acc[2] = {{0.f,0.f,0.f,0.f},{0.f,0.f,0.f,0.f}};
    const int ch0a = wave * 32;
    const int ch0b = wave * 32 + 16;

    // (A) bias GEMM: P[16 x 225] x Vb'_g[225 x 256], 8 k-chunks of 32
#pragma unroll
    for (int wk = 0; wk < 8; ++wk) {
        short8 pa_h = *(const short8*)&pah[n16 * 264 + wk * 32 + quad * 8];
        short8 pa_l = *(const short8*)&pal[n16 * 264 + wk * 32 + quad * 8];
        const long vb0 = (((long)(g * 256 + ch0a + n16)) << 8) + wk * 32 + quad * 8;
        const long vb1 = (((long)(g * 256 + ch0b + n16)) << 8) + wk * 32 + quad * 8;
        short8 b0h = *(const short8*)(Vbh + vb0);
        short8 b0l = *(const short8*)(Vbl + vb0);
        short8 b1h = *(const short8*)(Vbh + vb1);
        short8 b1l = *(const short8*)(Vbl + vb1);
        acc[0] = __builtin_amdgcn_mfma_f32_16x16x32_bf16(pa_h, b0h, acc[0], 0, 0, 0);
        acc[0] = __builtin_amdgcn_mfma_f32_16x16x32_bf16(pa_h, b0l, acc[0], 0, 0, 0);
        acc[0] = __builtin_amdgcn_mfma_f32_16x16x32_bf16(pa_l, b0h, acc[0], 0, 0, 0);
        acc[1] = __builtin_amdgcn_mfma_f32_16x16x32_bf16(pa_h, b1h, acc[1], 0, 0, 0);
        acc[1] = __builtin_amdgcn_mfma_f32_16x16x32_bf16(pa_h, b1l, acc[1], 0, 0, 0);
        acc[1] = __builtin_amdgcn_mfma_f32_16x16x32_bf16(pa_l, b1h, acc[1], 0, 0, 0);
    }

    // (V) banded GEMM per dy over V'_g (256 ch)
    for (int dy = 0; dy < 15; ++dy) {
        const int ky = y + dy - 7;
        if (ky < 0 || ky > 31) continue;
        short8 bnd_h, bnd_l;
        const int rowoff = n16 * 264 + dy * 15 - n16 - 1;
#pragma unroll
        for (int j = 0; j < 8; ++j) {
            int kk = quad * 8 + j;
            int dx = kk - n16 - 1;
            bool valid = (unsigned)dx < 15u;
            int idx = valid ? (rowoff + kk) : 0;
            short vh = pah[idx];
            short vl = pal[idx];
            bnd_h[j] = valid ? vh : (short)0;
            bnd_l[j] = valid ? vl : (short)0;
        }
        const long v0o = (((long)(bz * 256 + ch0a + n16)) * 32 + ky) * 48 + x0 + quad * 8;
        const long v1o = (((long)(bz * 256 + ch0b + n16)) * 32 + ky) * 48 + x0 + quad * 8;
        short8 v0h = *(const short8*)(vhi + v0o);
        short8 v0l = *(const short8*)(vlo + v0o);
        short8 v1h = *(const short8*)(vhi + v1o);
        short8 v1l = *(const short8*)(vlo + v1o);
        acc[0] = __builtin_amdgcn_mfma_f32_16x16x32_bf16(bnd_h, v0h, acc[0], 0, 0, 0);
        acc[0] = __builtin_amdgcn_mfma_f32_16x16x32_bf16(bnd_h, v0l, acc[0], 0, 0, 0);
        acc[0] = __builtin_amdgcn_mfma_f32_16x16x32_bf16(bnd_l, v0h, acc[0], 0, 0, 0);
        acc[1] = __builtin_amdgcn_mfma_f32_16x16x32_bf16(bnd_h, v1h, acc[1], 0, 0, 0);
        acc[1] = __builtin_amdgcn_mfma_f32_16x16x32_bf16(bnd_h, v1l, acc[1], 0, 0, 0);
        acc[1] = __builtin_amdgcn_mfma_f32_16x16x32_bf16(bnd_l, v1h, acc[1], 0, 0, 0);
    }

    // ---- phase F: atomicAdd final output (g==0 adds bfc) ----
    const int n = bz >> 1;
#pragma unroll
    for (int t = 0; t < 2; ++t) {
        const int d = (t ? ch0b : ch0a) + n16;
        const float badd = (g == 0) ? bfc[d] : 0.f;
#pragma unroll
        for (int r = 0; r < 4; ++r) {
            const int px = quad * 4 + r;
            long o = ((long)(y * 32 + x0 + px) * 4 + n) * 256 + d;
            atomicAdd(&out[o], acc[t][r] + badd);
        }
    }
}

// ---------------------------------------------------------------------------
// ws floats:
//   vhi@2097152 len 1572864 | vlo@3670016 len 1572864
//   Vbh@5242880 len 65536   | Vbl@5308416 len 65536 | bcw@5373952 len 512
//   qhi@6561792 qlo@7086080 khi@7610368 klo@8134656 (524288 each)
//   Whi@11804672 len 131072 (4 sels) | Wlo@11935744 len 131072
//   Wrh@13115392 len 30720 | Wrl@13146112 len 30720
// ---------------------------------------------------------------------------
extern "C" void kernel_launch(void* const* d_in, const int* in_sizes, int n_in,
                              void* d_out, int out_size, void* d_ws, size_t ws_size,
                              hipStream_t stream)
{
    const float* q    = (const float*)d_in[0];
    const float* k    = (const float*)d_in[1];
    const float* v    = (const float*)d_in[2];
    const float* Wq   = (const float*)d_in[3];
    const float* bq   = (const float*)d_in[4];
    const float* Wk   = (const float*)d_in[5];
    const float* bk   = (const float*)d_in[6];
    const float* Wv   = (const float*)d_in[7];
    const float* bv   = (const float*)d_in[8];
    const float* Wrel = (const float*)d_in[9];
    const float* brel = (const float*)d_in[10];
    const float* Vb   = (const float*)d_in[11];
    const float* Wfc  = (const float*)d_in[12];
    const float* bfc  = (const float*)d_in[13];
    float* out = (float*)d_out;

    float* ws   = (float*)d_ws;
    short* vhi  = (short*)(ws + 2097152);
    short* vlo  = (short*)(ws + 3670016);
    short* Vbh  = (short*)(ws + 5242880);
    short* Vbl  = (short*)(ws + 5308416);
    float* bcw  = ws + 5373952;
    short* qhi  = (short*)(ws + 6561792);
    short* qlo  = (short*)(ws + 7086080);
    short* khi  = (short*)(ws + 7610368);
    short* klo  = (short*)(ws + 8134656);
    short* Whi  = (short*)(ws + 11804672);
    short* Wlo  = (short*)(ws + 11935744);
    short* Wrh  = (short*)(ws + 13115392);
    short* Wrl  = (short*)(ws + 13146112);

    // out accumulates atomically -> zero first
    hipMemsetAsync(d_out, 0, out_size, stream);

    // weight-side prep: LDS-tiled Wc/bc/Vb' GEMMs + Wq/Wk/Wrel frags
    prep<<<dim3(158), dim3(256), 0, stream>>>(Wq, Wk, Wv, Wfc, Wrel, Vb, bv,
                                              Whi, Wlo, Wrh, Wrl, Vbh, Vbl, bcw);

    // projections q, k, v'g0, v'g1: 1024 blocks
    mfma_proj<<<dim3(64, 16), dim3(256), 0, stream>>>(q, k, v, Whi, Wlo,
                                                      bq, bk, bcw,
                                                      qhi, qlo, khi, klo,
                                                      vhi, vlo);

    // scores + softmax + folded PV -> final out (atomic): 512 x 512
    scores_pv<<<dim3(512), dim3(512), 0, stream>>>(qhi, qlo, khi, klo,
                                                   Wrh, Wrl, brel,
                                                   vhi, vlo, Vbh, Vbl,
                                                   bfc, out);
}

// Round 10
// 155.404 us; speedup vs baseline: 1.6867x; 1.2548x over previous
//
#include <hip/hip_runtime.h>
#include <math.h>

// N=4, C=256, H=W=32, NH=2, HD=128, MAX_DIS=7, WS=15, WW=225, T=sqrt(128)
// out: [hw=1024][n=4][c=256] fp32
// Round-10: revert Wfc fold (net -30 us, round 8/9 evidence). Best-of
// recombination: prep = frag-convert only; proj = pre-converted A-frags +
// coalesced V-transpose epilogue; scores = 512-thread 128ch MFMA-PV (48.4us,
// round 7); fc = 1024-block v2 (round 4).

typedef __attribute__((ext_vector_type(8))) short short8;
typedef __attribute__((ext_vector_type(4))) float floatx4;

__device__ __forceinline__ short f2bf(float f) {
    unsigned u = __float_as_uint(f);
    unsigned r = (u + 0x7fffu + ((u >> 16) & 1u)) >> 16;
    return (short)r;
}
__device__ __forceinline__ float bf2f(short s) {
    return __uint_as_float(((unsigned)(unsigned short)s) << 16);
}

// ---------------------------------------------------------------------------
// prep v3: pure fragment conversion (no GEMMs). 760 wave-units, 4/block,
// grid 190 x 256.
//  u [0,512)  : Wq/Wk/Wv/Wfc A-frags (sel = u>>7, dt/kc = u&127)
//  u [512,632): Wrel frags (g, wt, kc)
//  u [632,760): V_bias rows [g][128ch][256w] (w>=225 zero)
// ---------------------------------------------------------------------------
__global__ __launch_bounds__(256)
void prep(const float* __restrict__ Wq, const float* __restrict__ Wk,
          const float* __restrict__ Wv, const float* __restrict__ Wfc,
          const float* __restrict__ Wrel, const float* __restrict__ Vb,
          short* __restrict__ Whi, short* __restrict__ Wlo,
          short* __restrict__ Wrh, short* __restrict__ Wrl,
          short* __restrict__ Vbh, short* __restrict__ Vbl)
{
    const int tid = threadIdx.x;
    const int sub = tid >> 6, lane = tid & 63;
    const int n16 = lane & 15, quad = lane >> 4;
    const int u = blockIdx.x * 4 + sub;

    if (u < 512) {
        const int sel = u >> 7, rem = u & 127;
        const int dt = rem >> 3, kc = rem & 7;
        const float* W = (sel == 0 ? Wq : sel == 1 ? Wk : sel == 2 ? Wv : Wfc);
        const int d = dt * 16 + n16, cb = kc * 32 + quad * 8;
        float4 w0 = *(const float4*)&W[(long)d * 256 + cb];
        float4 w1 = *(const float4*)&W[(long)d * 256 + cb + 4];
        float f[8] = {w0.x, w0.y, w0.z, w0.w, w1.x, w1.y, w1.z, w1.w};
        short8 h8, l8;
#pragma unroll
        for (int j = 0; j < 8; ++j) {
            short hb = f2bf(f[j]);
            h8[j] = hb;
            l8[j] = f2bf(f[j] - bf2f(hb));
        }
        long off = (long)sel * 65536 + (((long)(dt * 8 + kc) * 64) + lane) * 8;
        *(short8*)(Whi + off) = h8;
        *(short8*)(Wlo + off) = l8;
    } else if (u < 632) {
        const int t = u - 512;
        const int g = t / 60, r = t - g * 60;
        const int wt = r >> 2, kc = r & 3;
        const int w = wt * 16 + n16;         // valid < 225
        const int cb = kc * 32 + quad * 8;
        float f[8] = {0.f, 0.f, 0.f, 0.f, 0.f, 0.f, 0.f, 0.f};
        if (w < 225) {
            float4 w0 = *(const float4*)&Wrel[(long)(g * 225 + w) * 128 + cb];
            float4 w1 = *(const float4*)&Wrel[(long)(g * 225 + w) * 128 + cb + 4];
            f[0] = w0.x; f[1] = w0.y; f[2] = w0.z; f[3] = w0.w;
            f[4] = w1.x; f[5] = w1.y; f[6] = w1.z; f[7] = w1.w;
        }
        short8 h8, l8;
#pragma unroll
        for (int j = 0; j < 8; ++j) {
            short hb = f2bf(f[j]);
            h8[j] = hb;
            l8[j] = f2bf(f[j] - bf2f(hb));
        }
        long off = (long)g * 30720 + (((long)(wt * 4 + kc) * 64) + lane) * 8;
        *(short8*)(Wrh + off) = h8;
        *(short8*)(Wrl + off) = l8;
    } else {
        const int t = u - 632;
        const int g = t >> 6, r = t & 63;
        const int dt = r >> 3, wk = r & 7;
        const int ch = dt * 16 + n16;
        const int w0 = wk * 32 + quad * 8;
        float f[8];
#pragma unroll
        for (int j = 0; j < 8; ++j) {
            int w = w0 + j;
            f[j] = (w < 225) ? Vb[(long)(g * 128 + ch) * 225 + w] : 0.f;
        }
        short8 h8, l8;
#pragma unroll
        for (int j = 0; j < 8; ++j) {
            short hb = f2bf(f[j]);
            h8[j] = hb;
            l8[j] = f2bf(f[j] - bf2f(hb));
        }
        long off = (((long)(g * 128 + ch)) << 8) + w0;
        *(short8*)(Vbh + off) = h8;
        *(short8*)(Vbl + off) = l8;
    }
}

// ---------------------------------------------------------------------------
// mfma_proj v8: pre-converted A-frags (prep), raw-input LDS staging.
// grid (64 mt16, 12 z); sel = z>>2: 0=q, 1=k, 2=v.
// sel 0/1 -> x-major bf16 hi/lo q/k (k * 1/T);
// sel 2   -> coalesced transposed bf16 V [bz 8][128 ch][32 y][48 x], pads 0.
// ---------------------------------------------------------------------------
__global__ __launch_bounds__(256)
void mfma_proj(const float* __restrict__ q, const float* __restrict__ k,
               const float* __restrict__ v,
               const short* __restrict__ Whi, const short* __restrict__ Wlo,
               const float* __restrict__ bq, const float* __restrict__ bk,
               const float* __restrict__ bv,
               short* __restrict__ qhi, short* __restrict__ qlo,
               short* __restrict__ khi, short* __restrict__ klo,
               short* __restrict__ vhi, short* __restrict__ vlo)
{
    __shared__ float st[256 * 17];       // staging [c 256][m 16 +1]; aliased as tile[16][257]
    const int tid = threadIdx.x;
    const int wave = tid >> 6, lane = tid & 63;
    const int n16 = lane & 15, quad = lane >> 4;
    const int mt16 = blockIdx.x, z = blockIdx.y;
    const int sel = z >> 2, batch = z & 3;

    const float* X = (sel == 0 ? q : sel == 1 ? k : v) + ((long)batch << 18);

    // ---- stage X tile: thread tid = channel c, 16 m's ----
    {
        const float* src = X + ((long)tid << 10) + mt16 * 16;
        float4 a0 = *(const float4*)(src);
        float4 a1 = *(const float4*)(src + 4);
        float4 a2 = *(const float4*)(src + 8);
        float4 a3 = *(const float4*)(src + 12);
        float* d = &st[tid * 17];
        d[0] = a0.x; d[1] = a0.y; d[2] = a0.z; d[3] = a0.w;
        d[4] = a1.x; d[5] = a1.y; d[6] = a1.z; d[7] = a1.w;
        d[8] = a2.x; d[9] = a2.y; d[10] = a2.z; d[11] = a2.w;
        d[12] = a3.x; d[13] = a3.y; d[14] = a3.z; d[15] = a3.w;
    }

    const float* bias = (sel == 0 ? bq : sel == 1 ? bk : bv);
    float bbv[4][4];
#pragma unroll
    for (int i = 0; i < 4; ++i) {
        float4 b4 = *(const float4*)&bias[(wave * 4 + i) * 16 + quad * 4];
        bbv[i][0] = b4.x; bbv[i][1] = b4.y; bbv[i][2] = b4.z; bbv[i][3] = b4.w;
    }
    __syncthreads();

    floatx4 acc[4] = {{0.f,0.f,0.f,0.f},{0.f,0.f,0.f,0.f},
                      {0.f,0.f,0.f,0.f},{0.f,0.f,0.f,0.f}};
    const long abase = (long)sel * 65536 + (long)lane * 8;
#pragma unroll
    for (int kc = 0; kc < 8; ++kc) {
        short8 bh, bl;
        const float* col = &st[(kc * 32 + quad * 8) * 17 + n16];
#pragma unroll
        for (int j = 0; j < 8; ++j) {
            float f = col[j * 17];
            short hb = f2bf(f);
            bh[j] = hb;
            bl[j] = f2bf(f - bf2f(hb));
        }
#pragma unroll
        for (int i = 0; i < 4; ++i) {
            const int dt = wave * 4 + i;
            short8 ahi = *(const short8*)(Whi + abase + (long)(dt * 8 + kc) * 512);
            short8 alo = *(const short8*)(Wlo + abase + (long)(dt * 8 + kc) * 512);
            acc[i] = __builtin_amdgcn_mfma_f32_16x16x32_bf16(ahi, bh, acc[i], 0, 0, 0);
            acc[i] = __builtin_amdgcn_mfma_f32_16x16x32_bf16(ahi, bl, acc[i], 0, 0, 0);
            acc[i] = __builtin_amdgcn_mfma_f32_16x16x32_bf16(alo, bh, acc[i], 0, 0, 0);
        }
    }

    // stage D[16 m][256 c] (alias st)
    __syncthreads();                      // st B-frag reads done
    float* tile = st;
#pragma unroll
    for (int i = 0; i < 4; ++i) {
        const int dt = wave * 4 + i;
#pragma unroll
        for (int r = 0; r < 4; ++r)
            tile[n16 * 257 + dt * 16 + quad * 4 + r] = acc[i][r] + bbv[i][r];
    }
    __syncthreads();

    if (sel == 2) {
        // coalesced transposed V write: thread = channel
        const int gg = tid >> 7, chp = tid & 127;
        const int yq = mt16 >> 1, xb = (mt16 & 1) * 16;
        short8 h0, h1, l0, l1;
#pragma unroll
        for (int j = 0; j < 8; ++j) {
            float f0 = tile[j * 257 + tid];
            float f1 = tile[(j + 8) * 257 + tid];
            short hb0 = f2bf(f0), hb1 = f2bf(f1);
            h0[j] = hb0; l0[j] = f2bf(f0 - bf2f(hb0));
            h1[j] = hb1; l1[j] = f2bf(f1 - bf2f(hb1));
        }
        long o = ((long)((batch * 2 + gg) * 128 + chp) * 32 + yq) * 48 + 8 + xb;
        *(short8*)(vhi + o) = h0;
        *(short8*)(vhi + o + 8) = h1;
        *(short8*)(vlo + o) = l0;
        *(short8*)(vlo + o + 8) = l1;
        // zero x-pads: this block zeroes (row = mt16>>1, side = mt16&1), all 256 ch
        const int prow = mt16 >> 1, side = mt16 & 1;
        long po = ((long)((batch * 2 + gg) * 128 + chp) * 32 + prow) * 48 + side * 40;
        short8 zz = {0,0,0,0,0,0,0,0};
        *(short8*)(vhi + po) = zz;
        *(short8*)(vlo + po) = zz;
        return;
    }

    const float scale = (sel == 1) ? 0.08838834764831845f : 1.0f;
    const int m_l = tid >> 4, c16 = (tid & 15) * 16;
    const int m = mt16 * 16 + m_l;
    short* oh = sel ? khi : qhi;
    short* ol = sel ? klo : qlo;
#pragma unroll
    for (int half = 0; half < 2; ++half) {
        const int cg = c16 + half * 8;
        short8 h8, l8;
#pragma unroll
        for (int j = 0; j < 8; ++j) {
            float f = tile[m_l * 257 + cg + j] * scale;
            short hb = f2bf(f);
            h8[j] = hb;
            l8[j] = f2bf(f - bf2f(hb));
        }
        const int g = cg >> 7, ch = cg & 127;
        const long base = (((long)(batch * 2 + g) << 10) + m) * 128 + ch;
        *(short8*)(oh + base) = h8;
        *(short8*)(ol + base) = l8;
    }
}

// ---------------------------------------------------------------------------
// scores_pv (round-7 verified, 48.4 us): 512 px-tiles x 512 threads (8 waves),
// XCD swizzle bz = lin&7. 128-ch MFMA PV + bias GEMM, AG frag output.
// ---------------------------------------------------------------------------
__global__ __launch_bounds__(512)
void scores_pv(const short* __restrict__ qhi, const short* __restrict__ qlo,
               const short* __restrict__ khi, const short* __restrict__ klo,
               const short* __restrict__ Wrh, const short* __restrict__ Wrl,
               const float* __restrict__ brel,
               const short* __restrict__ vhi, const short* __restrict__ vlo,
               const short* __restrict__ Vbh, const short* __restrict__ Vbl,
               short* __restrict__ AGhi, short* __restrict__ AGlo)
{
    __shared__ __align__(16) float qk[16 * 241];   // 15.4 KB; aliased as tile[16][133] in F
    __shared__ __align__(16) short pah[16 * 264];  // 8.25 KB  P hi (rows padded to 264)
    __shared__ __align__(16) short pal[16 * 264];  // 8.25 KB  P lo
    __shared__ float invl[16];

    const int tid = threadIdx.x;
    const int wave = tid >> 6, lane = tid & 63;     // wave 0..7
    const int lin = blockIdx.x;
    const int bz  = lin & 7;         // XCD-resident head/batch
    const int yy  = lin >> 3;        // 0..63
    const int y   = yy >> 1;
    const int xt  = yy & 1;
    const int g = bz & 1;
    const int x0 = xt * 16;

    const int n16 = lane & 15, quad = lane >> 4;
    const long qbase = (((long)bz << 10) + y * 32 + x0 + n16) * 128 + quad * 8;
    short8 a_hi[4], a_lo[4];
#pragma unroll
    for (int ch = 0; ch < 4; ++ch) {
        a_hi[ch] = *(const short8*)(qhi + qbase + ch * 32);
        a_lo[ch] = *(const short8*)(qlo + qbase + ch * 32);
    }

    // ---- phase R: rel logits (15 wt over 8 waves) ----
    for (int wt = wave; wt < 15; wt += 8) {
        const short* Ah = Wrh + (long)g * 30720 + ((long)(wt * 4) * 64 + lane) * 8;
        const short* Al = Wrl + (long)g * 30720 + ((long)(wt * 4) * 64 + lane) * 8;
        floatx4 racc = {0.f, 0.f, 0.f, 0.f};
#pragma unroll
        for (int kc = 0; kc < 4; ++kc) {
            short8 whh = *(const short8*)(Ah + kc * 512);
            short8 wll = *(const short8*)(Al + kc * 512);
            racc = __builtin_amdgcn_mfma_f32_16x16x32_bf16(whh, a_hi[kc], racc, 0, 0, 0);
            racc = __builtin_amdgcn_mfma_f32_16x16x32_bf16(whh, a_lo[kc], racc, 0, 0, 0);
            racc = __builtin_amdgcn_mfma_f32_16x16x32_bf16(wll, a_hi[kc], racc, 0, 0, 0);
        }
#pragma unroll
        for (int r = 0; r < 4; ++r) {
            int w = wt * 16 + quad * 4 + r;
            if (w < 225) {
                int dy = w / 15, dx = w - dy * 15;
                qk[n16 * 241 + dy * 16 + dx] = racc[r] + brel[g * 225 + w];
            }
        }
    }
    __syncthreads();

    // ---- phase M: mask invalid neighbors and pad slots ----
    for (int e = tid; e < 16 * 241; e += 512) {
        int px = e / 241, idx = e - px * 241;
        int dy = idx >> 4, dx = idx & 15;
        int hy = y + dy - 7, hx = x0 + px + dx - 7;
        bool valid = (dx < 15) && (dy < 15) &&
                     (hy >= 0) && (hy < 32) && (hx >= 0) && (hx < 32);
        if (!valid) qk[e] = -1e8f;
    }
    __syncthreads();

    // ---- phase B: band QK^T (15 dy over 8 waves) ----
    for (int dy = wave; dy < 15; dy += 8) {
        const int ky = y + dy - 7;
        if (ky < 0 || ky > 31) continue;
#pragma unroll
        for (int kxt = 0; kxt < 2; ++kxt) {
            const int kxg = x0 - 8 + kxt * 16 + n16;
            const long kb = (((long)bz << 10) + ky * 32 + kxg) * 128 + quad * 8;
            floatx4 acc = {0.f, 0.f, 0.f, 0.f};
#pragma unroll
            for (int ch = 0; ch < 4; ++ch) {
                short8 b_hi = *(const short8*)(khi + kb + ch * 32);
                short8 b_lo = *(const short8*)(klo + kb + ch * 32);
                acc = __builtin_amdgcn_mfma_f32_16x16x32_bf16(a_hi[ch], b_hi, acc, 0, 0, 0);
                acc = __builtin_amdgcn_mfma_f32_16x16x32_bf16(a_hi[ch], b_lo, acc, 0, 0, 0);
                acc = __builtin_amdgcn_mfma_f32_16x16x32_bf16(a_lo[ch], b_hi, acc, 0, 0, 0);
            }
            if (kxg >= 0 && kxg < 32) {
#pragma unroll
                for (int r = 0; r < 4; ++r) {
                    int m = quad * 4 + r;
                    int dx = kxg - (x0 + m) + 7;
                    if (dx >= 0 && dx < 15) {
                        int s = m * 241 + dy * 16 + dx;
                        qk[s] = qk[s] + acc[r];
                    }
                }
            }
        }
    }
    __syncthreads();

    // ---- softmax: 32 lanes per px row ----
    {
        int px = tid >> 5, s = tid & 31;
        float mx = -3.0e38f;
        for (int w = s; w < 240; w += 32) mx = fmaxf(mx, qk[px * 241 + w]);
#pragma unroll
        for (int msk = 16; msk; msk >>= 1) mx = fmaxf(mx, __shfl_xor(mx, msk));
        float sum = 0.f;
        for (int w = s; w < 240; w += 32) {
            float p = __expf(qk[px * 241 + w] - mx);
            qk[px * 241 + w] = p;
            sum += p;
        }
#pragma unroll
        for (int msk = 16; msk; msk >>= 1) sum += __shfl_xor(sum, msk);
        if (s == 0) invl[px] = 1.0f / sum;
    }
    __syncthreads();

    // ---- phase T: normalize + bf16 hi/lo into pah/pal (w >= 225 -> 0) ----
    for (int e = tid; e < 4096; e += 512) {
        int px = e >> 8, w = e & 255;
        float p = 0.f;
        if (w < 225) {
            int dy2 = w / 15, dx2 = w - dy2 * 15;
            p = qk[px * 241 + dy2 * 16 + dx2] * invl[px];
        }
        short hb = f2bf(p);
        pah[px * 264 + w] = hb;
        pal[px * 264 + w] = f2bf(p - bf2f(hb));
    }
    __syncthreads();
    // qk is dead from here on; tile aliases it in phase F.

    // ---- phases A+V: MFMA accumulation, 1 ch-tile per wave (8 tiles) ----
    floatx4 acc = {0.f, 0.f, 0.f, 0.f};
    const int ch0 = wave * 16;

    // (A) bias GEMM: P[16 x 225] x Vbh[225 x 128], 8 k-chunks of 32
#pragma unroll
    for (int wk = 0; wk < 8; ++wk) {
        short8 pa_h = *(const short8*)&pah[n16 * 264 + wk * 32 + quad * 8];
        short8 pa_l = *(const short8*)&pal[n16 * 264 + wk * 32 + quad * 8];
        const long vb0 = (((long)(g * 128 + ch0 + n16)) << 8) + wk * 32 + quad * 8;
        short8 b0h = *(const short8*)(Vbh + vb0);
        short8 b0l = *(const short8*)(Vbl + vb0);
        acc = __builtin_amdgcn_mfma_f32_16x16x32_bf16(pa_h, b0h, acc, 0, 0, 0);
        acc = __builtin_amdgcn_mfma_f32_16x16x32_bf16(pa_h, b0l, acc, 0, 0, 0);
        acc = __builtin_amdgcn_mfma_f32_16x16x32_bf16(pa_l, b0h, acc, 0, 0, 0);
    }

    // (V) banded GEMM per dy: P'[px][k] = P[px][dy*15 + k-px-1], k-cols x0-8..x0+23
    for (int dy = 0; dy < 15; ++dy) {
        const int ky = y + dy - 7;
        if (ky < 0 || ky > 31) continue;    // those P rows are exactly 0
        short8 bnd_h, bnd_l;
        const int rowoff = n16 * 264 + dy * 15 - n16 - 1;
#pragma unroll
        for (int j = 0; j < 8; ++j) {
            int kk = quad * 8 + j;
            int dx = kk - n16 - 1;
            bool valid = (unsigned)dx < 15u;
            int idx = valid ? (rowoff + kk) : 0;
            short vh = pah[idx];
            short vl = pal[idx];
            bnd_h[j] = valid ? vh : (short)0;
            bnd_l[j] = valid ? vl : (short)0;
        }
        const long v0o = (((long)((bz * 128 + ch0 + n16)) * 32 + ky)) * 48 + x0 + quad * 8;
        short8 v0h = *(const short8*)(vhi + v0o);
        short8 v0l = *(const short8*)(vlo + v0o);
        acc = __builtin_amdgcn_mfma_f32_16x16x32_bf16(bnd_h, v0h, acc, 0, 0, 0);
        acc = __builtin_amdgcn_mfma_f32_16x16x32_bf16(bnd_h, v0l, acc, 0, 0, 0);
        acc = __builtin_amdgcn_mfma_f32_16x16x32_bf16(bnd_l, v0h, acc, 0, 0, 0);
    }

    // ---- phase F: stage tile [16 px][128 ch] then AG frag conversion ----
    float* tile = qk;                    // [16][133]
    {
        const int cb = ch0 + n16;
#pragma unroll
        for (int r = 0; r < 4; ++r)
            tile[(quad * 4 + r) * 133 + cb] = acc[r];
    }
    __syncthreads();

    const int sub = tid >> 6;            // kcp: waves 0..3 write, 4..7 idle
    if (sub < 4) {
        short8 h8, l8;
#pragma unroll
        for (int j = 0; j < 8; ++j) {
            float f = tile[n16 * 133 + sub * 32 + quad * 8 + j];
            short hb = f2bf(f);
            h8[j] = hb;
            l8[j] = f2bf(f - bf2f(hb));
        }
        const int n = bz >> 1;
        const int mt16 = y * 2 + xt;
        const int kc = g * 4 + sub;
        long off = (long)n * 262144 + (((long)(mt16 * 8 + kc) * 64) + lane) * 8;
        *(short8*)(AGhi + off) = h8;
        *(short8*)(AGlo + off) = l8;
    }
}

// ---------------------------------------------------------------------------
// mfma_fc v2: one d-tile per wave. grid (mt16 64, db 4, nz 4) = 1024 blocks.
// ---------------------------------------------------------------------------
__global__ __launch_bounds__(256)
void mfma_fc(const short* __restrict__ Ahi, const short* __restrict__ Alo,
             const short* __restrict__ Whi, const short* __restrict__ Wlo,
             const float* __restrict__ bfc, float* __restrict__ out)
{
    __shared__ float tile[16 * 68];
    const int tid = threadIdx.x;
    const int wave = tid >> 6, lane = tid & 63;
    const int n16 = lane & 15, quad = lane >> 4;
    const int mt16 = blockIdx.x, db = blockIdx.y, nz = blockIdx.z;
    const int dt = db * 4 + wave;

    const short* Ah = Whi + (long)3 * 65536 + ((long)(dt * 8) * 64 + lane) * 8;
    const short* Al = Wlo + (long)3 * 65536 + ((long)(dt * 8) * 64 + lane) * 8;
    const short* Bh = Ahi + (long)nz * 262144;
    const short* Bl = Alo + (long)nz * 262144;

    float4 bv4 = *(const float4*)&bfc[dt * 16 + quad * 4];
    float bb[4] = {bv4.x, bv4.y, bv4.z, bv4.w};

    floatx4 acc = {0.f, 0.f, 0.f, 0.f};
#pragma unroll
    for (int kc = 0; kc < 8; ++kc) {
        short8 ahi = *(const short8*)(Ah + kc * 512);
        short8 alo = *(const short8*)(Al + kc * 512);
        long bo = ((long)(mt16 * 8 + kc) * 64 + lane) * 8;
        short8 bh = *(const short8*)(Bh + bo);
        short8 bl = *(const short8*)(Bl + bo);
        acc = __builtin_amdgcn_mfma_f32_16x16x32_bf16(ahi, bh, acc, 0, 0, 0);
        acc = __builtin_amdgcn_mfma_f32_16x16x32_bf16(ahi, bl, acc, 0, 0, 0);
        acc = __builtin_amdgcn_mfma_f32_16x16x32_bf16(alo, bh, acc, 0, 0, 0);
    }

    const int dl = wave * 16 + quad * 4;
#pragma unroll
    for (int r = 0; r < 4; ++r)
        tile[n16 * 68 + dl + r] = acc[r] + bb[r];
    __syncthreads();

    const int mm = tid >> 4, d4 = (tid & 15) * 4;
    float4 o4 = *(const float4*)&tile[mm * 68 + d4];
    *(float4*)&out[(long)(mt16 * 16 + mm) * 1024 + nz * 256 + db * 64 + d4] = o4;
}

// ---------------------------------------------------------------------------
// ws floats:
//   vhi@2097152 (786432 fl as shorts) vlo@2883584
//   Vbh@4718592 (32768 fl) Vbl@4751360
//   qhi@6561792 qlo@7086080 khi@7610368 klo@8134656 (524288 each)
//   Whi@11804672 (131072, 4 sels) Wlo@11935744
//   AGhi@12066816 (524288) AGlo@12591104
//   Wrh@13115392 (30720) Wrl@13146112
// ---------------------------------------------------------------------------
extern "C" void kernel_launch(void* const* d_in, const int* in_sizes, int n_in,
                              void* d_out, int out_size, void* d_ws, size_t ws_size,
                              hipStream_t stream)
{
    const float* q    = (const float*)d_in[0];
    const float* k    = (const float*)d_in[1];
    const float* v    = (const float*)d_in[2];
    const float* Wq   = (const float*)d_in[3];
    const float* bq   = (const float*)d_in[4];
    const float* Wk   = (const float*)d_in[5];
    const float* bk   = (const float*)d_in[6];
    const float* Wv   = (const float*)d_in[7];
    const float* bv   = (const float*)d_in[8];
    const float* Wrel = (const float*)d_in[9];
    const float* brel = (const float*)d_in[10];
    const float* Vb   = (const float*)d_in[11];
    const float* Wfc  = (const float*)d_in[12];
    const float* bfc  = (const float*)d_in[13];
    float* out = (float*)d_out;

    float* ws   = (float*)d_ws;
    short* vhi  = (short*)(ws + 2097152);
    short* vlo  = (short*)(ws + 2883584);
    short* Vbh  = (short*)(ws + 4718592);
    short* Vbl  = (short*)(ws + 4751360);
    short* qhi  = (short*)(ws + 6561792);
    short* qlo  = (short*)(ws + 7086080);
    short* khi  = (short*)(ws + 7610368);
    short* klo  = (short*)(ws + 8134656);
    short* Whi  = (short*)(ws + 11804672);
    short* Wlo  = (short*)(ws + 11935744);
    short* AGhi = (short*)(ws + 12066816);
    short* AGlo = (short*)(ws + 12591104);
    short* Wrh  = (short*)(ws + 13115392);
    short* Wrl  = (short*)(ws + 13146112);

    // fragment conversion: Wq/Wk/Wv/Wfc A-frags, Wrel, V_bias rows
    prep<<<dim3(190), dim3(256), 0, stream>>>(Wq, Wk, Wv, Wfc, Wrel, Vb,
                                              Whi, Wlo, Wrh, Wrl, Vbh, Vbl);

    // QKV projections (pre-converted A-frags): 768 blocks
    mfma_proj<<<dim3(64, 12), dim3(256), 0, stream>>>(q, k, v, Whi, Wlo,
                                                      bq, bk, bv,
                                                      qhi, qlo, khi, klo,
                                                      vhi, vlo);

    // rel + scores + softmax + MFMA PV -> AG frags: 512 x 512 threads
    scores_pv<<<dim3(512), dim3(512), 0, stream>>>(qhi, qlo, khi, klo,
                                                   Wrh, Wrl, brel,
                                                   vhi, vlo, Vbh, Vbl,
                                                   AGhi, AGlo);

    // FC via MFMA: 1024 blocks (4/CU)
    mfma_fc<<<dim3(64, 4, 4), dim3(256), 0, stream>>>(AGhi, AGlo, Whi, Wlo,
                                                      bfc, out);
}